// Round 7
// baseline (298.768 us; speedup 1.0000x reference)
//
#include <hip/hip_runtime.h>
#include <stdint.h>

#define ENC_D 512
#define ATTN_D 512
#define STR_D 256
#define CELL_D 512
#define BATCH 64
#define SEQ 1024
#define NROWS (BATCH * SEQ)

typedef __bf16 bf16x8 __attribute__((ext_vector_type(8)));
typedef float f32x4 __attribute__((ext_vector_type(4)));

__device__ __forceinline__ unsigned short f2bf(float f) {
    unsigned int u = __float_as_uint(f);
    u += 0x7fffu + ((u >> 16) & 1u);   // RNE
    return (unsigned short)(u >> 16);
}

__device__ __forceinline__ void lds_cp16(void* l, const void* g) {
    __builtin_amdgcn_global_load_lds(
        (const __attribute__((address_space(1))) unsigned int*)g,
        (__attribute__((address_space(3))) unsigned int*)l, 16, 0, 0);
}

// ---------------------------------------------------------------------------
// Kernel 1 (fused): blocks 0..63   : WF = bf16(W_enc^T) fragment-linear
//                   blocks 64..831 : bias partials [jq][b][a] (12 slabs)
//                   blocks 832..847: zero d_out (atomicAdd target for K3)
// WF granule (16 B) = 8 k-elems of one column; gi = nt*1024 + ks*64 + quad*16 + c.
// ---------------------------------------------------------------------------
__global__ __launch_bounds__(256) void k_prep(const float* __restrict__ W,
                                              unsigned short* __restrict__ WF,
                                              const float* __restrict__ str,
                                              const float* __restrict__ cell,
                                              const float* __restrict__ Wstr,
                                              const float* __restrict__ Wcell,
                                              float* __restrict__ bpart,
                                              float* __restrict__ outz) {
    __shared__ char smraw[64 * 68 * 2];        // 8704 B, reused per role
    const int bx = blockIdx.x, t = threadIdx.x;

    if (bx < 64) {
        // ---- W transpose+convert to fragment-linear ----
        unsigned short* T = (unsigned short*)smraw;   // [n_local][e_local] stride 68
        const int ei = bx >> 3, ni = bx & 7;
        const int e0 = ei * 64, n0 = ni * 64;
#pragma unroll
        for (int i = 0; i < 4; ++i) {
            const int idx = t + i * 256;
            const int r = idx >> 4, c4 = idx & 15;
            const float4 v = *(const float4*)(W + (size_t)(e0 + r) * ATTN_D + n0 + c4 * 4);
            T[(c4 * 4 + 0) * 68 + r] = f2bf(v.x);
            T[(c4 * 4 + 1) * 68 + r] = f2bf(v.y);
            T[(c4 * 4 + 2) * 68 + r] = f2bf(v.z);
            T[(c4 * 4 + 3) * 68 + r] = f2bf(v.w);
        }
        __syncthreads();
#pragma unroll
        for (int i = 0; i < 2; ++i) {
            const int q = t + i * 256;
            const int n = q >> 3, ge = q & 7;
            union { unsigned short s[8]; uint4 u; } o;
#pragma unroll
            for (int j = 0; j < 8; ++j) o.s[j] = T[n * 68 + ge * 8 + j];
            const int ng = n0 + n;
            const int g = ei * 8 + ge;
            const int nt = ng >> 4, c = ng & 15;
            const int ks = g >> 2, quad = g & 3;
            const int gi = nt * 1024 + ks * 64 + quad * 16 + c;
            *(uint4*)(WF + (size_t)gi * 8) = o.u;
        }
    } else if (bx < 832) {
        // ---- bias partial: slab jq (64 j-rows), batch b ----
        float* sj = (float*)smraw;          // 64 floats
        float* red = (float*)smraw + 64;    // 512 floats
        const int q = bx - 64;
        const int b = q / 12, jq = q - b * 12;
        const float* hvec;
        const float* Wbase;
        if (jq < 4) { hvec = str + b * STR_D + jq * 64;         Wbase = Wstr + (size_t)(jq * 64) * ATTN_D; }
        else        { hvec = cell + b * CELL_D + (jq - 4) * 64; Wbase = Wcell + (size_t)((jq - 4) * 64) * ATTN_D; }
        if (t < 64) sj[t] = hvec[t];
        __syncthreads();
        const int h = t >> 7, a4 = t & 127;
        f32x4 acc = {0.f, 0.f, 0.f, 0.f};
#pragma unroll 8
        for (int i = h * 32; i < h * 32 + 32; ++i) {
            const float s = sj[i];
            const float4 wv = *(const float4*)(Wbase + (size_t)i * ATTN_D + a4 * 4);
            acc[0] += s * wv.x; acc[1] += s * wv.y; acc[2] += s * wv.z; acc[3] += s * wv.w;
        }
        if (h == 1) *(f32x4*)(red + a4 * 4) = acc;
        __syncthreads();
        if (h == 0) {
            const f32x4 o = *(const f32x4*)(red + a4 * 4);
            acc[0] += o[0]; acc[1] += o[1]; acc[2] += o[2]; acc[3] += o[3];
            *(f32x4*)(bpart + (size_t)(jq * BATCH + b) * ATTN_D + a4 * 4) = acc;
        }
    } else {
        // ---- zero out (K3 atomic target) ----
        const f32x4 z = {0.f, 0.f, 0.f, 0.f};
        float* p = outz + (size_t)(bx - 832) * 2048 + t * 8;
        *(f32x4*)p = z;
        *(f32x4*)(p + 4) = z;
    }
}

// ---------------------------------------------------------------------------
// Kernel 2: fused scores GEMM. 1024 blocks x 128 threads (2 waves), M=64.
// Prologue: bias finalize (3 vecs + 12 slabs -> LDS) + Wcomb->LDS, overlapping
// chunk-0 async staging. Wave owns 32 rows of A in regs (128 VGPR, Mw=2).
// 32 N-chunks of 16 cols; B dbuf 2x16 KB via flat async copy of frag-linear WF;
// lane-linear ds_read_b128, zero bank conflicts. launch_bounds(128,1): 512-VGPR
// cap so the A-fragments NEVER spill (round-6's (128,2) forced 128 + scratch).
// ---------------------------------------------------------------------------
__global__ __launch_bounds__(128, 1) void k_scores(const float* __restrict__ E,
                                                   const unsigned short* __restrict__ WF,
                                                   const float* __restrict__ bpart,
                                                   const float* __restrict__ b_enc,
                                                   const float* __restrict__ b_str,
                                                   const float* __restrict__ b_cell,
                                                   const float* __restrict__ Wcomb,
                                                   float* __restrict__ scores) {
    __shared__ unsigned short buf[2][8192];     // 2 x 16 KB
    __shared__ float sbias[512];
    __shared__ float sWc[512];

    const int tid = threadIdx.x;
    const int r0 = blockIdx.x * 64;
    const int b = blockIdx.x >> 4;              // 16 blocks per batch
    const int w = tid >> 6, lane = tid & 63;
    const int quad = lane >> 4, c = lane & 15;

    // stage chunk 0 (async, 16 KB)
#pragma unroll
    for (int i = 0; i < 8; ++i)
        lds_cp16((char*)&buf[0][0] + i * 2048 + tid * 16,
                 (const char*)WF + i * 2048 + tid * 16);

    // bias finalize into LDS (overlaps staging): a = tid*4
    {
        const int a = tid * 4;
        const float4 be = *(const float4*)(b_enc + a);
        const float4 bs = *(const float4*)(b_str + a);
        const float4 bc = *(const float4*)(b_cell + a);
        f32x4 s;
        s[0] = be.x + bs.x + bc.x; s[1] = be.y + bs.y + bc.y;
        s[2] = be.z + bs.z + bc.z; s[3] = be.w + bs.w + bc.w;
#pragma unroll
        for (int jq = 0; jq < 12; ++jq) {
            const float4 p = *(const float4*)(bpart + (size_t)(jq * BATCH + b) * ATTN_D + a);
            s[0] += p.x; s[1] += p.y; s[2] += p.z; s[3] += p.w;
        }
        *(f32x4*)(sbias + a) = s;
        const float4 wcv = *(const float4*)(Wcomb + a);
        f32x4 wc4; wc4[0] = wcv.x; wc4[1] = wcv.y; wc4[2] = wcv.z; wc4[3] = wcv.w;
        *(f32x4*)(sWc + a) = wc4;
    }

    // load A: 2 M-tiles x full K in registers (E read exactly once)
    bf16x8 afr[2][16];
#pragma unroll
    for (int m = 0; m < 2; ++m) {
        const float* Ep = E + (size_t)(r0 + w * 32 + m * 16 + c) * ENC_D + quad * 8;
#pragma unroll
        for (int ks = 0; ks < 16; ++ks) {
            const float4 v0 = *(const float4*)(Ep + ks * 32);
            const float4 v1 = *(const float4*)(Ep + ks * 32 + 4);
            union { unsigned short s[8]; bf16x8 v; } u;
            u.s[0] = f2bf(v0.x); u.s[1] = f2bf(v0.y);
            u.s[2] = f2bf(v0.z); u.s[3] = f2bf(v0.w);
            u.s[4] = f2bf(v1.x); u.s[5] = f2bf(v1.y);
            u.s[6] = f2bf(v1.z); u.s[7] = f2bf(v1.w);
            afr[m][ks] = u.v;
        }
    }

    float sc0[4] = {0.f, 0.f, 0.f, 0.f};
    float sc1[4] = {0.f, 0.f, 0.f, 0.f};

    __syncthreads();   // chunk 0 staged + sbias/sWc visible

    for (int ch = 0; ch < 32; ++ch) {
        if (ch < 31) {
            const char* gsrc = (const char*)WF + (size_t)(ch + 1) * 16384;
            char* ldst = (char*)&buf[(ch + 1) & 1][0];
#pragma unroll
            for (int i = 0; i < 8; ++i)
                lds_cp16(ldst + i * 2048 + tid * 16, gsrc + i * 2048 + tid * 16);
        }

        const unsigned short* wb = &buf[ch & 1][0];
        f32x4 a0 = {0.f, 0.f, 0.f, 0.f}, a1 = {0.f, 0.f, 0.f, 0.f};
#pragma unroll
        for (int ks = 0; ks < 16; ++ks) {
            const bf16x8 b0 = *(const bf16x8*)(wb + (ks * 64 + lane) * 8);
            a0 = __builtin_amdgcn_mfma_f32_16x16x32_bf16(afr[0][ks], b0, a0, 0, 0, 0);
            a1 = __builtin_amdgcn_mfma_f32_16x16x32_bf16(afr[1][ks], b0, a1, 0, 0, 0);
        }

        const int n = ch * 16 + c;
        const float bi = sbias[n], wc = sWc[n];
#pragma unroll
        for (int r = 0; r < 4; ++r) {
            float v;
            v = a0[r] + bi; sc0[r] += (v > 0.f ? v : 0.f) * wc;
            v = a1[r] + bi; sc1[r] += (v > 0.f ? v : 0.f) * wc;
        }
        __syncthreads();
    }

    // reduce across the 16 column-lanes
#pragma unroll
    for (int r = 0; r < 4; ++r) {
        float v0 = sc0[r], v1 = sc1[r];
        v0 += __shfl_xor(v0, 1); v1 += __shfl_xor(v1, 1);
        v0 += __shfl_xor(v0, 2); v1 += __shfl_xor(v1, 2);
        v0 += __shfl_xor(v0, 4); v1 += __shfl_xor(v1, 4);
        sc0[r] = v0 + __shfl_xor(v0, 8);
        sc1[r] = v1 + __shfl_xor(v1, 8);
    }
    if (c == 0) {
        const int g0 = r0 + w * 32 + quad * 4;
#pragma unroll
        for (int r = 0; r < 4; ++r) scores[g0 + r] = sc0[r];
#pragma unroll
        for (int r = 0; r < 4; ++r) scores[g0 + 16 + r] = sc1[r];
    }
}

// ---------------------------------------------------------------------------
// Kernel 3: fused softmax + context + reduce. 1024 blocks x 128 threads;
// block (b, lo): softmax over the full 1024-row score vector (redundant per
// block, cheap), then weighted sum of its 64 L-rows, atomicAdd into out
// (zeroed by K1). Eliminates separate softmax + part + reduce kernels.
// ---------------------------------------------------------------------------
__global__ __launch_bounds__(128) void k_ctx(const float* __restrict__ E,
                                             const float* __restrict__ scores,
                                             float* __restrict__ out) {
    __shared__ float ex[1024];
    __shared__ float rtmp[4];
    const int blk = blockIdx.x, t = threadIdx.x;
    const int b = blk >> 4, lo = blk & 15;

    float v[8];
    float m = -1e30f;
#pragma unroll
    for (int i = 0; i < 8; ++i) {
        v[i] = scores[b * SEQ + i * 128 + t];
        m = fmaxf(m, v[i]);
    }
#pragma unroll
    for (int o = 32; o > 0; o >>= 1) m = fmaxf(m, __shfl_xor(m, o));
    if ((t & 63) == 0) rtmp[t >> 6] = m;
    __syncthreads();
    m = fmaxf(rtmp[0], rtmp[1]);

    float s = 0.f;
#pragma unroll
    for (int i = 0; i < 8; ++i) {
        const float e = __expf(v[i] - m);
        ex[i * 128 + t] = e;
        s += e;
    }
#pragma unroll
    for (int o = 32; o > 0; o >>= 1) s += __shfl_xor(s, o);
    if ((t & 63) == 0) rtmp[2 + (t >> 6)] = s;
    __syncthreads();
    const float inv = 1.f / (rtmp[2] + rtmp[3]);

    const float* Ep = E + (size_t)(b * SEQ + lo * 64) * ENC_D + t * 4;
    f32x4 acc = {0.f, 0.f, 0.f, 0.f};
#pragma unroll 8
    for (int l = 0; l < 64; ++l) {
        const float4 e4 = *(const float4*)(Ep + (size_t)l * ENC_D);
        const float wv = ex[lo * 64 + l];
        acc[0] += wv * e4.x; acc[1] += wv * e4.y;
        acc[2] += wv * e4.z; acc[3] += wv * e4.w;
    }
    float* op = out + b * ENC_D + t * 4;
    atomicAdd(op + 0, acc[0] * inv);
    atomicAdd(op + 1, acc[1] * inv);
    atomicAdd(op + 2, acc[2] * inv);
    atomicAdd(op + 3, acc[3] * inv);
}

// ---------------------------------------------------------------------------
extern "C" void kernel_launch(void* const* d_in, const int* in_sizes, int n_in,
                              void* d_out, int out_size, void* d_ws, size_t ws_size,
                              hipStream_t stream) {
    const float* E      = (const float*)d_in[0];
    const float* str    = (const float*)d_in[1];
    const float* cell   = (const float*)d_in[2];
    const float* Wenc   = (const float*)d_in[3];
    const float* b_enc  = (const float*)d_in[4];
    const float* b_str  = (const float*)d_in[5];
    const float* Wcell  = (const float*)d_in[7];
    const float* Wstr   = (const float*)d_in[5];
    // careful: input order is W_enc, b_enc, W_str, b_str, W_cell, b_cell, W_comb, b_comb
    const float* Wstr_  = (const float*)d_in[5];
    const float* bstr_  = (const float*)d_in[6];
    const float* Wcell_ = (const float*)d_in[7];
    const float* bcell_ = (const float*)d_in[8];
    const float* Wcomb  = (const float*)d_in[9];
    // d_in[10] = b_comb: uniform pre-softmax shift — no effect, skipped.
    float* out = (float*)d_out;

    char* ws = (char*)d_ws;
    unsigned short* WF = (unsigned short*)ws;                 // 512 KB (frag-linear)
    float* scores = (float*)(ws + (512 << 10));               // 256 KB
    float* bpart  = (float*)(ws + (512 << 10) + (256 << 10)); // 1.5 MB

    k_prep<<<848, 256, 0, stream>>>(Wenc, WF, str, cell, Wstr_, Wcell_, bpart, out);
    k_scores<<<NROWS / 64, 128, 0, stream>>>(E, WF, bpart, b_enc, bstr_, bcell_, Wcomb, scores);
    k_ctx<<<1024, 128, 0, stream>>>(E, scores, out);
    (void)Wstr; (void)Wcell; (void)b_str;
}

// Round 8
// 281.601 us; speedup vs baseline: 1.0610x; 1.0610x over previous
//
#include <hip/hip_runtime.h>
#include <stdint.h>

#define ENC_D 512
#define ATTN_D 512
#define STR_D 256
#define CELL_D 512
#define BATCH 64
#define SEQ 1024
#define NROWS (BATCH * SEQ)

typedef __bf16 bf16x8 __attribute__((ext_vector_type(8)));
typedef float f32x4 __attribute__((ext_vector_type(4)));

__device__ __forceinline__ unsigned short f2bf(float f) {
    unsigned int u = __float_as_uint(f);
    u += 0x7fffu + ((u >> 16) & 1u);   // RNE
    return (unsigned short)(u >> 16);
}

__device__ __forceinline__ void lds_cp16(void* l, const void* g) {
    __builtin_amdgcn_global_load_lds(
        (const __attribute__((address_space(1))) unsigned int*)g,
        (__attribute__((address_space(3))) unsigned int*)l, 16, 0, 0);
}

// ---------------------------------------------------------------------------
// Kernel 1 (fused): blocks 0..63   : WF = bf16(W_enc^T) fragment-linear
//                   blocks 64..831 : bias partials [jq][b][a] (12 slabs)
//                   blocks 832..847: zero d_out (atomicAdd target for K3)
// WF granule (16 B) = 8 k-elems of one column; gi = nt*1024 + ks*64 + quad*16 + c.
// ---------------------------------------------------------------------------
__global__ __launch_bounds__(256) void k_prep(const float* __restrict__ W,
                                              unsigned short* __restrict__ WF,
                                              const float* __restrict__ str,
                                              const float* __restrict__ cell,
                                              const float* __restrict__ Wstr,
                                              const float* __restrict__ Wcell,
                                              float* __restrict__ bpart,
                                              float* __restrict__ outz) {
    __shared__ char smraw[64 * 68 * 2];        // 8704 B, reused per role
    const int bx = blockIdx.x, t = threadIdx.x;

    if (bx < 64) {
        unsigned short* T = (unsigned short*)smraw;   // [n_local][e_local] stride 68
        const int ei = bx >> 3, ni = bx & 7;
        const int e0 = ei * 64, n0 = ni * 64;
#pragma unroll
        for (int i = 0; i < 4; ++i) {
            const int idx = t + i * 256;
            const int r = idx >> 4, c4 = idx & 15;
            const float4 v = *(const float4*)(W + (size_t)(e0 + r) * ATTN_D + n0 + c4 * 4);
            T[(c4 * 4 + 0) * 68 + r] = f2bf(v.x);
            T[(c4 * 4 + 1) * 68 + r] = f2bf(v.y);
            T[(c4 * 4 + 2) * 68 + r] = f2bf(v.z);
            T[(c4 * 4 + 3) * 68 + r] = f2bf(v.w);
        }
        __syncthreads();
#pragma unroll
        for (int i = 0; i < 2; ++i) {
            const int q = t + i * 256;
            const int n = q >> 3, ge = q & 7;
            union { unsigned short s[8]; uint4 u; } o;
#pragma unroll
            for (int j = 0; j < 8; ++j) o.s[j] = T[n * 68 + ge * 8 + j];
            const int ng = n0 + n;
            const int g = ei * 8 + ge;
            const int nt = ng >> 4, c = ng & 15;
            const int ks = g >> 2, quad = g & 3;
            const int gi = nt * 1024 + ks * 64 + quad * 16 + c;
            *(uint4*)(WF + (size_t)gi * 8) = o.u;
        }
    } else if (bx < 832) {
        float* sj = (float*)smraw;          // 64 floats
        float* red = (float*)smraw + 64;    // 512 floats
        const int q = bx - 64;
        const int b = q / 12, jq = q - b * 12;
        const float* hvec;
        const float* Wbase;
        if (jq < 4) { hvec = str + b * STR_D + jq * 64;         Wbase = Wstr + (size_t)(jq * 64) * ATTN_D; }
        else        { hvec = cell + b * CELL_D + (jq - 4) * 64; Wbase = Wcell + (size_t)((jq - 4) * 64) * ATTN_D; }
        if (t < 64) sj[t] = hvec[t];
        __syncthreads();
        const int h = t >> 7, a4 = t & 127;
        f32x4 acc = {0.f, 0.f, 0.f, 0.f};
#pragma unroll 8
        for (int i = h * 32; i < h * 32 + 32; ++i) {
            const float s = sj[i];
            const float4 wv = *(const float4*)(Wbase + (size_t)i * ATTN_D + a4 * 4);
            acc[0] += s * wv.x; acc[1] += s * wv.y; acc[2] += s * wv.z; acc[3] += s * wv.w;
        }
        if (h == 1) *(f32x4*)(red + a4 * 4) = acc;
        __syncthreads();
        if (h == 0) {
            const f32x4 o = *(const f32x4*)(red + a4 * 4);
            acc[0] += o[0]; acc[1] += o[1]; acc[2] += o[2]; acc[3] += o[3];
            *(f32x4*)(bpart + (size_t)(jq * BATCH + b) * ATTN_D + a4 * 4) = acc;
        }
    } else {
        const f32x4 z = {0.f, 0.f, 0.f, 0.f};
        float* p = outz + (size_t)(bx - 832) * 2048 + t * 8;
        *(f32x4*)p = z;
        *(f32x4*)(p + 4) = z;
    }
}

// ---------------------------------------------------------------------------
// Kernel 2: fused scores GEMM. 256 blocks x 512 threads (8 waves), M=256.
// Exactly 1 block/CU (grid == CU count): W restage traffic drops 4x vs r7
// (256 x 512 KB = 128 MB L2 total; 16 KB/CU/chunk), and the per-chunk compute
// (8 waves x 32 MFMA) now covers the staging drain. Wave owns 32 rows of A in
// regs (128 VGPR, Mw=2); B dbuf 2x16 KB via flat async copy of frag-linear WF;
// lane-linear ds_read_b128, zero bank conflicts. launch_bounds(512,2):
// VGPR cap 256 -> no spill at ~185 VGPR, 2 waves/SIMD.
// ---------------------------------------------------------------------------
__global__ __launch_bounds__(512, 2) void k_scores(const float* __restrict__ E,
                                                   const unsigned short* __restrict__ WF,
                                                   const float* __restrict__ bpart,
                                                   const float* __restrict__ b_enc,
                                                   const float* __restrict__ b_str,
                                                   const float* __restrict__ b_cell,
                                                   const float* __restrict__ Wcomb,
                                                   float* __restrict__ scores) {
    __shared__ unsigned short buf[2][8192];     // 2 x 16 KB
    __shared__ float sbias[512];
    __shared__ float sWc[512];

    const int tid = threadIdx.x;
    const int r0 = blockIdx.x * 256;
    const int b = blockIdx.x >> 2;              // 4 blocks per batch
    const int w = tid >> 6, lane = tid & 63;
    const int quad = lane >> 4, c = lane & 15;

    // stage chunk 0 (async, 16 KB = 2 issues x 512 thr x 16 B)
#pragma unroll
    for (int i = 0; i < 2; ++i)
        lds_cp16((char*)&buf[0][0] + i * 8192 + tid * 16,
                 (const char*)WF + i * 8192 + tid * 16);

    // bias finalize into LDS (overlaps staging)
    if (tid < 128) {
        const int a = tid * 4;
        const float4 be = *(const float4*)(b_enc + a);
        const float4 bs = *(const float4*)(b_str + a);
        const float4 bc = *(const float4*)(b_cell + a);
        f32x4 s;
        s[0] = be.x + bs.x + bc.x; s[1] = be.y + bs.y + bc.y;
        s[2] = be.z + bs.z + bc.z; s[3] = be.w + bs.w + bc.w;
#pragma unroll
        for (int jq = 0; jq < 12; ++jq) {
            const float4 p = *(const float4*)(bpart + (size_t)(jq * BATCH + b) * ATTN_D + a);
            s[0] += p.x; s[1] += p.y; s[2] += p.z; s[3] += p.w;
        }
        *(f32x4*)(sbias + a) = s;
        const float4 wcv = *(const float4*)(Wcomb + a);
        f32x4 wc4; wc4[0] = wcv.x; wc4[1] = wcv.y; wc4[2] = wcv.z; wc4[3] = wcv.w;
        *(f32x4*)(sWc + a) = wc4;
    }

    // load A: 2 M-tiles x full K in registers (E read exactly once)
    bf16x8 afr[2][16];
#pragma unroll
    for (int m = 0; m < 2; ++m) {
        const float* Ep = E + (size_t)(r0 + w * 32 + m * 16 + c) * ENC_D + quad * 8;
#pragma unroll
        for (int ks = 0; ks < 16; ++ks) {
            const float4 v0 = *(const float4*)(Ep + ks * 32);
            const float4 v1 = *(const float4*)(Ep + ks * 32 + 4);
            union { unsigned short s[8]; bf16x8 v; } u;
            u.s[0] = f2bf(v0.x); u.s[1] = f2bf(v0.y);
            u.s[2] = f2bf(v0.z); u.s[3] = f2bf(v0.w);
            u.s[4] = f2bf(v1.x); u.s[5] = f2bf(v1.y);
            u.s[6] = f2bf(v1.z); u.s[7] = f2bf(v1.w);
            afr[m][ks] = u.v;
        }
    }

    float sc0[4] = {0.f, 0.f, 0.f, 0.f};
    float sc1[4] = {0.f, 0.f, 0.f, 0.f};

    __syncthreads();   // chunk 0 staged + sbias/sWc visible

    for (int ch = 0; ch < 32; ++ch) {
        if (ch < 31) {
            const char* gsrc = (const char*)WF + (size_t)(ch + 1) * 16384;
            char* ldst = (char*)&buf[(ch + 1) & 1][0];
#pragma unroll
            for (int i = 0; i < 2; ++i)
                lds_cp16(ldst + i * 8192 + tid * 16, gsrc + i * 8192 + tid * 16);
        }

        const unsigned short* wb = &buf[ch & 1][0];
        f32x4 a0 = {0.f, 0.f, 0.f, 0.f}, a1 = {0.f, 0.f, 0.f, 0.f};
#pragma unroll
        for (int ks = 0; ks < 16; ++ks) {
            const bf16x8 b0 = *(const bf16x8*)(wb + (ks * 64 + lane) * 8);
            a0 = __builtin_amdgcn_mfma_f32_16x16x32_bf16(afr[0][ks], b0, a0, 0, 0, 0);
            a1 = __builtin_amdgcn_mfma_f32_16x16x32_bf16(afr[1][ks], b0, a1, 0, 0, 0);
        }

        const int n = ch * 16 + c;
        const float bi = sbias[n], wc = sWc[n];
#pragma unroll
        for (int r = 0; r < 4; ++r) {
            float v;
            v = a0[r] + bi; sc0[r] += (v > 0.f ? v : 0.f) * wc;
            v = a1[r] + bi; sc1[r] += (v > 0.f ? v : 0.f) * wc;
        }
        __syncthreads();
    }

    // reduce across the 16 column-lanes
#pragma unroll
    for (int r = 0; r < 4; ++r) {
        float v0 = sc0[r], v1 = sc1[r];
        v0 += __shfl_xor(v0, 1); v1 += __shfl_xor(v1, 1);
        v0 += __shfl_xor(v0, 2); v1 += __shfl_xor(v1, 2);
        v0 += __shfl_xor(v0, 4); v1 += __shfl_xor(v1, 4);
        sc0[r] = v0 + __shfl_xor(v0, 8);
        sc1[r] = v1 + __shfl_xor(v1, 8);
    }
    if (c == 0) {
        const int g0 = r0 + w * 32 + quad * 4;
#pragma unroll
        for (int r = 0; r < 4; ++r) scores[g0 + r] = sc0[r];
#pragma unroll
        for (int r = 0; r < 4; ++r) scores[g0 + 16 + r] = sc1[r];
    }
}

// ---------------------------------------------------------------------------
// Kernel 3: fused softmax + context + reduce. 1024 blocks x 128 threads;
// block (b, lo): softmax over the full 1024 scores (redundant per block,
// cheap), weighted sum of its 64 L-rows, atomicAdd into out (zeroed by K1).
// ---------------------------------------------------------------------------
__global__ __launch_bounds__(128) void k_ctx(const float* __restrict__ E,
                                             const float* __restrict__ scores,
                                             float* __restrict__ out) {
    __shared__ float ex[1024];
    __shared__ float rtmp[4];
    const int blk = blockIdx.x, t = threadIdx.x;
    const int b = blk >> 4, lo = blk & 15;

    float v[8];
    float m = -1e30f;
#pragma unroll
    for (int i = 0; i < 8; ++i) {
        v[i] = scores[b * SEQ + i * 128 + t];
        m = fmaxf(m, v[i]);
    }
#pragma unroll
    for (int o = 32; o > 0; o >>= 1) m = fmaxf(m, __shfl_xor(m, o));
    if ((t & 63) == 0) rtmp[t >> 6] = m;
    __syncthreads();
    m = fmaxf(rtmp[0], rtmp[1]);

    float s = 0.f;
#pragma unroll
    for (int i = 0; i < 8; ++i) {
        const float e = __expf(v[i] - m);
        ex[i * 128 + t] = e;
        s += e;
    }
#pragma unroll
    for (int o = 32; o > 0; o >>= 1) s += __shfl_xor(s, o);
    if ((t & 63) == 0) rtmp[2 + (t >> 6)] = s;
    __syncthreads();
    const float inv = 1.f / (rtmp[2] + rtmp[3]);

    const float* Ep = E + (size_t)(b * SEQ + lo * 64) * ENC_D + t * 4;
    f32x4 acc = {0.f, 0.f, 0.f, 0.f};
#pragma unroll 8
    for (int l = 0; l < 64; ++l) {
        const float4 e4 = *(const float4*)(Ep + (size_t)l * ENC_D);
        const float wv = ex[lo * 64 + l];
        acc[0] += wv * e4.x; acc[1] += wv * e4.y;
        acc[2] += wv * e4.z; acc[3] += wv * e4.w;
    }
    float* op = out + b * ENC_D + t * 4;
    atomicAdd(op + 0, acc[0] * inv);
    atomicAdd(op + 1, acc[1] * inv);
    atomicAdd(op + 2, acc[2] * inv);
    atomicAdd(op + 3, acc[3] * inv);
}

// ---------------------------------------------------------------------------
extern "C" void kernel_launch(void* const* d_in, const int* in_sizes, int n_in,
                              void* d_out, int out_size, void* d_ws, size_t ws_size,
                              hipStream_t stream) {
    const float* E      = (const float*)d_in[0];
    const float* str    = (const float*)d_in[1];
    const float* cell   = (const float*)d_in[2];
    const float* Wenc   = (const float*)d_in[3];
    const float* b_enc  = (const float*)d_in[4];
    const float* Wstr   = (const float*)d_in[5];
    const float* b_str  = (const float*)d_in[6];
    const float* Wcell  = (const float*)d_in[7];
    const float* b_cell = (const float*)d_in[8];
    const float* Wcomb  = (const float*)d_in[9];
    // d_in[10] = b_comb: uniform pre-softmax shift — no effect, skipped.
    float* out = (float*)d_out;

    char* ws = (char*)d_ws;
    unsigned short* WF = (unsigned short*)ws;                 // 512 KB (frag-linear)
    float* scores = (float*)(ws + (512 << 10));               // 256 KB
    float* bpart  = (float*)(ws + (512 << 10) + (256 << 10)); // 1.5 MB

    k_prep<<<848, 256, 0, stream>>>(Wenc, WF, str, cell, Wstr, Wcell, bpart, out);
    k_scores<<<NROWS / 256, 512, 0, stream>>>(E, WF, bpart, b_enc, b_str, b_cell, Wcomb, scores);
    k_ctx<<<1024, 128, 0, stream>>>(E, scores, out);
}

// Round 11
// 274.699 us; speedup vs baseline: 1.0876x; 1.0251x over previous
//
#include <hip/hip_runtime.h>
#include <stdint.h>

#define ENC_D 512
#define ATTN_D 512
#define STR_D 256
#define CELL_D 512
#define BATCH 64
#define SEQ 1024
#define NROWS (BATCH * SEQ)

typedef __bf16 bf16x8 __attribute__((ext_vector_type(8)));
typedef float f32x4 __attribute__((ext_vector_type(4)));

__device__ __forceinline__ unsigned short f2bf(float f) {
    unsigned int u = __float_as_uint(f);
    u += 0x7fffu + ((u >> 16) & 1u);   // RNE
    return (unsigned short)(u >> 16);
}

__device__ __forceinline__ void lds_cp16(void* l, const void* g) {
    __builtin_amdgcn_global_load_lds(
        (const __attribute__((address_space(1))) unsigned int*)g,
        (__attribute__((address_space(3))) unsigned int*)l, 16, 0, 0);
}

// Fused waitcnt+barrier as ONE asm with a memory clobber: the clobber is the
// compiler fence (bare builtins are not), the vmcnt(N) leaves the newest
// prefetch in flight across the barrier (no full drain).
#define BAR_VM4() asm volatile("s_waitcnt vmcnt(4)\n\ts_barrier" ::: "memory")
#define BAR_VM0() asm volatile("s_waitcnt vmcnt(0)\n\ts_barrier" ::: "memory")

// ---------------------------------------------------------------------------
// Kernel 1 (fused): blocks 0..63   : WF = bf16(W_enc^T) fragment-linear
//                   blocks 64..831 : bias partials [jq][b][a] (12 slabs)
//                   blocks 832..847: zero d_out (atomicAdd target for K3)
// WF granule (16 B) = 8 k-elems of one column; gi = nt*1024 + ks*64 + quad*16 + c.
// ---------------------------------------------------------------------------
__global__ __launch_bounds__(256) void k_prep(const float* __restrict__ W,
                                              unsigned short* __restrict__ WF,
                                              const float* __restrict__ str,
                                              const float* __restrict__ cell,
                                              const float* __restrict__ Wstr,
                                              const float* __restrict__ Wcell,
                                              float* __restrict__ bpart,
                                              float* __restrict__ outz) {
    __shared__ char smraw[64 * 68 * 2];        // 8704 B, reused per role
    const int bx = blockIdx.x, t = threadIdx.x;

    if (bx < 64) {
        unsigned short* T = (unsigned short*)smraw;   // [n_local][e_local] stride 68
        const int ei = bx >> 3, ni = bx & 7;
        const int e0 = ei * 64, n0 = ni * 64;
#pragma unroll
        for (int i = 0; i < 4; ++i) {
            const int idx = t + i * 256;
            const int r = idx >> 4, c4 = idx & 15;
            const float4 v = *(const float4*)(W + (size_t)(e0 + r) * ATTN_D + n0 + c4 * 4);
            T[(c4 * 4 + 0) * 68 + r] = f2bf(v.x);
            T[(c4 * 4 + 1) * 68 + r] = f2bf(v.y);
            T[(c4 * 4 + 2) * 68 + r] = f2bf(v.z);
            T[(c4 * 4 + 3) * 68 + r] = f2bf(v.w);
        }
        __syncthreads();
#pragma unroll
        for (int i = 0; i < 2; ++i) {
            const int q = t + i * 256;
            const int n = q >> 3, ge = q & 7;
            union { unsigned short s[8]; uint4 u; } o;
#pragma unroll
            for (int j = 0; j < 8; ++j) o.s[j] = T[n * 68 + ge * 8 + j];
            const int ng = n0 + n;
            const int g = ei * 8 + ge;
            const int nt = ng >> 4, c = ng & 15;
            const int ks = g >> 2, quad = g & 3;
            const int gi = nt * 1024 + ks * 64 + quad * 16 + c;
            *(uint4*)(WF + (size_t)gi * 8) = o.u;
        }
    } else if (bx < 832) {
        float* sj = (float*)smraw;          // 64 floats
        float* red = (float*)smraw + 64;    // 512 floats
        const int q = bx - 64;
        const int b = q / 12, jq = q - b * 12;
        const float* hvec;
        const float* Wbase;
        if (jq < 4) { hvec = str + b * STR_D + jq * 64;         Wbase = Wstr + (size_t)(jq * 64) * ATTN_D; }
        else        { hvec = cell + b * CELL_D + (jq - 4) * 64; Wbase = Wcell + (size_t)((jq - 4) * 64) * ATTN_D; }
        if (t < 64) sj[t] = hvec[t];
        __syncthreads();
        const int h = t >> 7, a4 = t & 127;
        f32x4 acc = {0.f, 0.f, 0.f, 0.f};
#pragma unroll 8
        for (int i = h * 32; i < h * 32 + 32; ++i) {
            const float s = sj[i];
            const float4 wv = *(const float4*)(Wbase + (size_t)i * ATTN_D + a4 * 4);
            acc[0] += s * wv.x; acc[1] += s * wv.y; acc[2] += s * wv.z; acc[3] += s * wv.w;
        }
        if (h == 1) *(f32x4*)(red + a4 * 4) = acc;
        __syncthreads();
        if (h == 0) {
            const f32x4 o = *(const f32x4*)(red + a4 * 4);
            acc[0] += o[0]; acc[1] += o[1]; acc[2] += o[2]; acc[3] += o[3];
            *(f32x4*)(bpart + (size_t)(jq * BATCH + b) * ATTN_D + a4 * 4) = acc;
        }
    } else {
        const f32x4 z = {0.f, 0.f, 0.f, 0.f};
        float* p = outz + (size_t)(bx - 832) * 2048 + t * 8;
        *(f32x4*)p = z;
        *(f32x4*)(p + 4) = z;
    }
}

// ---------------------------------------------------------------------------
// Kernel 2: fused scores GEMM. 256 blocks x 512 threads (8 waves), M=256,
// 1 block/CU. 16 chunks of 32 cols; 3-deep staging ring (3 x 32 KB).
// Iteration ch: issue async staging for ch+2 (4 loads/thread), compute ch
// (16 ds_read_b128 + 32 MFMA in 8 chains), then vmcnt(4)+s_barrier in one
// fenced asm: chunk ch+1 landed, ch+2 still in flight. Per-wave vmcnt ledger:
// 4 outstanding -> +4 issued -> wait(4) leaves exactly the newest 4.
// launch_bounds(512,1): VGPR cap 256, no spill (r8 spilled at cap 128).
// ---------------------------------------------------------------------------
__global__ __launch_bounds__(512, 1) void k_scores(const float* __restrict__ E,
                                                   const unsigned short* __restrict__ WF,
                                                   const float* __restrict__ bpart,
                                                   const float* __restrict__ b_enc,
                                                   const float* __restrict__ b_str,
                                                   const float* __restrict__ b_cell,
                                                   const float* __restrict__ Wcomb,
                                                   float* __restrict__ scores) {
    __shared__ unsigned short buf[3][16384];    // 3 x 32 KB
    __shared__ float sbias[512];
    __shared__ float sWc[512];

    const int tid = threadIdx.x;
    const int r0 = blockIdx.x * 256;
    const int b = blockIdx.x >> 2;              // 4 blocks per batch
    const int w = tid >> 6, lane = tid & 63;
    const int quad = lane >> 4, c = lane & 15;

    // stage chunks 0 and 1 (async, 2 x 32 KB = 4 issues x 512 thr x 16 B each)
#pragma unroll
    for (int p = 0; p < 2; ++p)
#pragma unroll
        for (int i = 0; i < 4; ++i)
            lds_cp16((char*)&buf[p][0] + i * 8192 + tid * 16,
                     (const char*)WF + (size_t)p * 32768 + i * 8192 + tid * 16);

    // bias finalize into LDS (overlaps staging)
    if (tid < 128) {
        const int a = tid * 4;
        const float4 be = *(const float4*)(b_enc + a);
        const float4 bs = *(const float4*)(b_str + a);
        const float4 bc = *(const float4*)(b_cell + a);
        f32x4 s;
        s[0] = be.x + bs.x + bc.x; s[1] = be.y + bs.y + bc.y;
        s[2] = be.z + bs.z + bc.z; s[3] = be.w + bs.w + bc.w;
#pragma unroll
        for (int jq = 0; jq < 12; ++jq) {
            const float4 p = *(const float4*)(bpart + (size_t)(jq * BATCH + b) * ATTN_D + a);
            s[0] += p.x; s[1] += p.y; s[2] += p.z; s[3] += p.w;
        }
        *(f32x4*)(sbias + a) = s;
        const float4 wcv = *(const float4*)(Wcomb + a);
        f32x4 wc4; wc4[0] = wcv.x; wc4[1] = wcv.y; wc4[2] = wcv.z; wc4[3] = wcv.w;
        *(f32x4*)(sWc + a) = wc4;
    }

    // load A: 2 M-tiles x full K in registers (E read exactly once)
    bf16x8 afr[2][16];
#pragma unroll
    for (int m = 0; m < 2; ++m) {
        const float* Ep = E + (size_t)(r0 + w * 32 + m * 16 + c) * ENC_D + quad * 8;
#pragma unroll
        for (int ks = 0; ks < 16; ++ks) {
            const float4 v0 = *(const float4*)(Ep + ks * 32);
            const float4 v1 = *(const float4*)(Ep + ks * 32 + 4);
            union { unsigned short s[8]; bf16x8 v; } u;
            u.s[0] = f2bf(v0.x); u.s[1] = f2bf(v0.y);
            u.s[2] = f2bf(v0.z); u.s[3] = f2bf(v0.w);
            u.s[4] = f2bf(v1.x); u.s[5] = f2bf(v1.y);
            u.s[6] = f2bf(v1.z); u.s[7] = f2bf(v1.w);
            afr[m][ks] = u.v;
        }
    }

    float sc0[4] = {0.f, 0.f, 0.f, 0.f};
    float sc1[4] = {0.f, 0.f, 0.f, 0.f};

    __syncthreads();   // one full drain: chunks 0,1 staged; sbias/sWc visible

    int cbuf = 0, sbuf = 2;
    for (int ch = 0; ch < 16; ++ch) {
        // issue async staging for chunk ch+2 into the free ring slot
        if (ch < 14) {
            const char* gsrc = (const char*)WF + (size_t)(ch + 2) * 32768;
            char* ldst = (char*)&buf[sbuf][0];
#pragma unroll
            for (int i = 0; i < 4; ++i)
                lds_cp16(ldst + i * 8192 + tid * 16, gsrc + i * 8192 + tid * 16);
        }

        // compute chunk ch (8 independent accumulator chains)
        // buffer layout: nt0 granules at short-offset 0, nt1 at +8192 (16 KB)
        const unsigned short* wb = &buf[cbuf][0];
        f32x4 a0e = {0.f,0.f,0.f,0.f}, a0o = {0.f,0.f,0.f,0.f};
        f32x4 a1e = {0.f,0.f,0.f,0.f}, a1o = {0.f,0.f,0.f,0.f};
        f32x4 b0e = {0.f,0.f,0.f,0.f}, b0o = {0.f,0.f,0.f,0.f};
        f32x4 b1e = {0.f,0.f,0.f,0.f}, b1o = {0.f,0.f,0.f,0.f};
#pragma unroll
        for (int ks = 0; ks < 16; ks += 2) {
            const bf16x8 f0 = *(const bf16x8*)(wb + (ks * 64 + lane) * 8);
            const bf16x8 f1 = *(const bf16x8*)(wb + ((ks + 1) * 64 + lane) * 8);
            const bf16x8 g0 = *(const bf16x8*)(wb + 8192 + (ks * 64 + lane) * 8);
            const bf16x8 g1 = *(const bf16x8*)(wb + 8192 + ((ks + 1) * 64 + lane) * 8);
            a0e = __builtin_amdgcn_mfma_f32_16x16x32_bf16(afr[0][ks], f0, a0e, 0, 0, 0);
            a1e = __builtin_amdgcn_mfma_f32_16x16x32_bf16(afr[1][ks], f0, a1e, 0, 0, 0);
            a0o = __builtin_amdgcn_mfma_f32_16x16x32_bf16(afr[0][ks + 1], f1, a0o, 0, 0, 0);
            a1o = __builtin_amdgcn_mfma_f32_16x16x32_bf16(afr[1][ks + 1], f1, a1o, 0, 0, 0);
            b0e = __builtin_amdgcn_mfma_f32_16x16x32_bf16(afr[0][ks], g0, b0e, 0, 0, 0);
            b1e = __builtin_amdgcn_mfma_f32_16x16x32_bf16(afr[1][ks], g0, b1e, 0, 0, 0);
            b0o = __builtin_amdgcn_mfma_f32_16x16x32_bf16(afr[0][ks + 1], g1, b0o, 0, 0, 0);
            b1o = __builtin_amdgcn_mfma_f32_16x16x32_bf16(afr[1][ks + 1], g1, b1o, 0, 0, 0);
        }

        // epilogue: bias + relu + dot(W_comb)
        const int n0 = ch * 32 + c;
        const float bi0 = sbias[n0], wc0 = sWc[n0];
        const float bi1 = sbias[n0 + 16], wc1 = sWc[n0 + 16];
#pragma unroll
        for (int r = 0; r < 4; ++r) {
            float v;
            v = (a0e[r] + a0o[r]) + bi0; sc0[r] += (v > 0.f ? v : 0.f) * wc0;
            v = (b0e[r] + b0o[r]) + bi1; sc0[r] += (v > 0.f ? v : 0.f) * wc1;
            v = (a1e[r] + a1o[r]) + bi0; sc1[r] += (v > 0.f ? v : 0.f) * wc0;
            v = (b1e[r] + b1o[r]) + bi1; sc1[r] += (v > 0.f ? v : 0.f) * wc1;
        }

        // rotate ring; fenced barrier keeping the newest prefetch in flight
        cbuf = (cbuf == 2) ? 0 : cbuf + 1;
        sbuf = (sbuf == 2) ? 0 : sbuf + 1;
        if (ch < 15) {
            if (ch < 14) BAR_VM4();
            else         BAR_VM0();
        }
    }

    // reduce across the 16 column-lanes
#pragma unroll
    for (int r = 0; r < 4; ++r) {
        float v0 = sc0[r], v1 = sc1[r];
        v0 += __shfl_xor(v0, 1); v1 += __shfl_xor(v1, 1);
        v0 += __shfl_xor(v0, 2); v1 += __shfl_xor(v1, 2);
        v0 += __shfl_xor(v0, 4); v1 += __shfl_xor(v1, 4);
        sc0[r] = v0 + __shfl_xor(v0, 8);
        sc1[r] = v1 + __shfl_xor(v1, 8);
    }
    if (c == 0) {
        const int g0 = r0 + w * 32 + quad * 4;
#pragma unroll
        for (int r = 0; r < 4; ++r) scores[g0 + r] = sc0[r];
#pragma unroll
        for (int r = 0; r < 4; ++r) scores[g0 + 16 + r] = sc1[r];
    }
}

// ---------------------------------------------------------------------------
// Kernel 3: fused softmax + context + reduce. 1024 blocks x 128 threads;
// block (b, lo): softmax over the full 1024 scores (redundant per block,
// cheap), weighted sum of its 64 L-rows, atomicAdd into out (zeroed by K1).
// ---------------------------------------------------------------------------
__global__ __launch_bounds__(128) void k_ctx(const float* __restrict__ E,
                                             const float* __restrict__ scores,
                                             float* __restrict__ out) {
    __shared__ float ex[1024];
    __shared__ float rtmp[4];
    const int blk = blockIdx.x, t = threadIdx.x;
    const int b = blk >> 4, lo = blk & 15;

    float v[8];
    float m = -1e30f;
#pragma unroll
    for (int i = 0; i < 8; ++i) {
        v[i] = scores[b * SEQ + i * 128 + t];
        m = fmaxf(m, v[i]);
    }
#pragma unroll
    for (int o = 32; o > 0; o >>= 1) m = fmaxf(m, __shfl_xor(m, o));
    if ((t & 63) == 0) rtmp[t >> 6] = m;
    __syncthreads();
    m = fmaxf(rtmp[0], rtmp[1]);

    float s = 0.f;
#pragma unroll
    for (int i = 0; i < 8; ++i) {
        const float e = __expf(v[i] - m);
        ex[i * 128 + t] = e;
        s += e;
    }
#pragma unroll
    for (int o = 32; o > 0; o >>= 1) s += __shfl_xor(s, o);
    if ((t & 63) == 0) rtmp[2 + (t >> 6)] = s;
    __syncthreads();
    const float inv = 1.f / (rtmp[2] + rtmp[3]);

    const float* Ep = E + (size_t)(b * SEQ + lo * 64) * ENC_D + t * 4;
    f32x4 acc = {0.f, 0.f, 0.f, 0.f};
#pragma unroll 8
    for (int l = 0; l < 64; ++l) {
        const float4 e4 = *(const float4*)(Ep + (size_t)l * ENC_D);
        const float wv = ex[lo * 64 + l];
        acc[0] += wv * e4.x; acc[1] += wv * e4.y;
        acc[2] += wv * e4.z; acc[3] += wv * e4.w;
    }
    float* op = out + b * ENC_D + t * 4;
    atomicAdd(op + 0, acc[0] * inv);
    atomicAdd(op + 1, acc[1] * inv);
    atomicAdd(op + 2, acc[2] * inv);
    atomicAdd(op + 3, acc[3] * inv);
}

// ---------------------------------------------------------------------------
extern "C" void kernel_launch(void* const* d_in, const int* in_sizes, int n_in,
                              void* d_out, int out_size, void* d_ws, size_t ws_size,
                              hipStream_t stream) {
    const float* E      = (const float*)d_in[0];
    const float* str    = (const float*)d_in[1];
    const float* cell   = (const float*)d_in[2];
    const float* Wenc   = (const float*)d_in[3];
    const float* b_enc  = (const float*)d_in[4];
    const float* Wstr   = (const float*)d_in[5];
    const float* b_str  = (const float*)d_in[6];
    const float* Wcell  = (const float*)d_in[7];
    const float* b_cell = (const float*)d_in[8];
    const float* Wcomb  = (const float*)d_in[9];
    // d_in[10] = b_comb: uniform pre-softmax shift — no effect, skipped.
    float* out = (float*)d_out;

    char* ws = (char*)d_ws;
    unsigned short* WF = (unsigned short*)ws;                 // 512 KB (frag-linear)
    float* scores = (float*)(ws + (512 << 10));               // 256 KB
    float* bpart  = (float*)(ws + (512 << 10) + (256 << 10)); // 1.5 MB

    k_prep<<<848, 256, 0, stream>>>(Wenc, WF, str, cell, Wstr, Wcell, bpart, out);
    k_scores<<<NROWS / 256, 512, 0, stream>>>(E, WF, bpart, b_enc, b_str, b_cell, Wcomb, scores);
    k_ctx<<<1024, 128, 0, stream>>>(E, scores, out);
}